// Round 1
// baseline (1701.638 us; speedup 1.0000x reference)
//
#include <hip/hip_runtime.h>
#include <hip/hip_bf16.h>

#define N_NODES 100000
#define N_EDGES 1600000

// ---------------- CSR build ----------------

__global__ void hist_kernel(const int* __restrict__ dst, int* __restrict__ deg, int e) {
    int i = blockIdx.x * blockDim.x + threadIdx.x;
    if (i < e) atomicAdd(&deg[dst[i]], 1);
}

// single-block scan over n elements (n ~ 100k), 1024 threads
__global__ void scan_kernel(const int* __restrict__ deg, int* __restrict__ row_off,
                            int* __restrict__ cursor, int n) {
    __shared__ int sh[1024];
    int tid = threadIdx.x;
    int running = 0;
    for (int base = 0; base < n; base += 1024) {
        int i = base + tid;
        int d = (i < n) ? deg[i] : 0;
        sh[tid] = d;
        __syncthreads();
        int v = d;
        for (int off = 1; off < 1024; off <<= 1) {
            int t = (tid >= off) ? sh[tid - off] : 0;
            __syncthreads();
            v += t;
            sh[tid] = v;
            __syncthreads();
        }
        // v = inclusive scan of this chunk; sh[1023] = chunk total
        if (i < n) {
            int excl = running + v - d;
            row_off[i] = excl;
            cursor[i]  = excl;
        }
        running += sh[1023];
        __syncthreads();
    }
    if (tid == 0) row_off[n] = running;
}

__global__ void fill_kernel(const int* __restrict__ src, const int* __restrict__ dst,
                            int* __restrict__ cursor, int* __restrict__ src_sorted, int e) {
    int i = blockIdx.x * blockDim.x + threadIdx.x;
    if (i < e) {
        int pos = atomicAdd(&cursor[dst[i]], 1);
        src_sorted[pos] = src[i];
    }
}

// ---------------- neighbor sum (gather) ----------------
// one wave (64 lanes) per node; lane = channel

template <int C>
__global__ void agg_kernel(const float* __restrict__ xin, const int* __restrict__ row_off,
                           const int* __restrict__ src_sorted, float* __restrict__ agg, int n) {
    int wid  = (blockIdx.x * blockDim.x + threadIdx.x) >> 6;
    int lane = threadIdx.x & 63;
    if (wid >= n) return;
    int start = row_off[wid], end = row_off[wid + 1];
    float acc = 0.f;
    for (int base = start; base < end; base += 64) {
        int cnt = min(64, end - base);
        int sid = (lane < cnt) ? src_sorted[base + lane] : 0;
        for (int j = 0; j < cnt; ++j) {
            int s = __shfl(sid, j);
            if (lane < C) acc += xin[s * C + lane];
        }
    }
    if (lane < C) agg[wid * C + lane] = acc;
}

// ---------------- node transform ----------------
// h = relu(mean_agg @ w_l^T + b + h_in @ w_r^T); optionally fused final FC (64->3)
// one wave per node; lane = output channel

template <int CIN, bool LAST>
__global__ void xform_kernel(const float* __restrict__ agg, const float* __restrict__ hin,
                             const int* __restrict__ row_off,
                             const float* __restrict__ w_l, const float* __restrict__ b,
                             const float* __restrict__ w_r,
                             const float* __restrict__ fc_w, const float* __restrict__ fc_b,
                             float* __restrict__ hout, float* __restrict__ out, int n) {
    __shared__ float wlT[CIN][64];
    __shared__ float wrT[CIN][64];
    for (int idx = threadIdx.x; idx < 64 * CIN; idx += blockDim.x) {
        int c = idx / CIN, k = idx % CIN;       // w is [64][CIN] row-major
        wlT[k][c] = w_l[idx];
        wrT[k][c] = w_r[idx];
    }
    __syncthreads();

    int node = blockIdx.x * (blockDim.x >> 6) + (threadIdx.x >> 6);
    int lane = threadIdx.x & 63;
    if (node >= n) return;

    int deg = row_off[node + 1] - row_off[node];
    float rscale = 1.0f / (float)max(deg, 1);

    float av = (lane < CIN) ? agg[node * CIN + lane] * rscale : 0.f;
    float hv = (lane < CIN) ? hin[node * CIN + lane] : 0.f;

    float acc = b[lane];
#pragma unroll
    for (int k = 0; k < CIN; ++k) {
        float a = __shfl(av, k);
        float h = __shfl(hv, k);
        acc += a * wlT[k][lane] + h * wrT[k][lane];
    }
    float hval = fmaxf(acc, 0.f);

    if (!LAST) {
        hout[node * 64 + lane] = hval;
    } else {
#pragma unroll
        for (int o = 0; o < 3; ++o) {
            float p = hval * fc_w[o * 64 + lane];
#pragma unroll
            for (int s = 32; s > 0; s >>= 1) p += __shfl_xor(p, s);
            if (lane == 0) out[node * 3 + o] = p + fc_b[o];
        }
    }
}

// ---------------- launch ----------------

extern "C" void kernel_launch(void* const* d_in, const int* in_sizes, int n_in,
                              void* d_out, int out_size, void* d_ws, size_t ws_size,
                              hipStream_t stream) {
    const float* x    = (const float*)d_in[0];
    const int*   ei   = (const int*)d_in[1];
    const float* w1_l = (const float*)d_in[2];
    const float* b1   = (const float*)d_in[3];
    const float* w1_r = (const float*)d_in[4];
    const float* w2_l = (const float*)d_in[5];
    const float* b2   = (const float*)d_in[6];
    const float* w2_r = (const float*)d_in[7];
    const float* w3_l = (const float*)d_in[8];
    const float* b3   = (const float*)d_in[9];
    const float* w3_r = (const float*)d_in[10];
    const float* fc_w = (const float*)d_in[11];
    const float* fc_b = (const float*)d_in[12];
    float* out = (float*)d_out;

    const int N = N_NODES;
    const int E = N_EDGES;
    const int* src = ei;
    const int* dst = ei + E;

    // workspace bump allocator (256B aligned)
    size_t off = 0;
    auto alloc = [&](size_t bytes) -> void* {
        void* p = (char*)d_ws + off;
        off += (bytes + 255) & ~size_t(255);
        return p;
    };
    int*   deg        = (int*)alloc(N * sizeof(int));
    int*   row_off    = (int*)alloc((N + 1) * sizeof(int));
    int*   cursor     = (int*)alloc(N * sizeof(int));
    int*   src_sorted = (int*)alloc(E * sizeof(int));
    float* agg        = (float*)alloc((size_t)N * 64 * sizeof(float));
    float* hA         = (float*)alloc((size_t)N * 64 * sizeof(float));
    float* hB         = (float*)alloc((size_t)N * 64 * sizeof(float));

    int nb_e = (E + 255) / 256;
    int nb_n = (N + 3) / 4;   // 4 waves (nodes) per 256-thread block

    hipMemsetAsync(deg, 0, N * sizeof(int), stream);
    hist_kernel<<<nb_e, 256, 0, stream>>>(dst, deg, E);
    scan_kernel<<<1, 1024, 0, stream>>>(deg, row_off, cursor, N);
    fill_kernel<<<nb_e, 256, 0, stream>>>(src, dst, cursor, src_sorted, E);

    // layer 1 (6 -> 64)
    agg_kernel<6><<<nb_n, 256, 0, stream>>>(x, row_off, src_sorted, agg, N);
    xform_kernel<6, false><<<nb_n, 256, 0, stream>>>(agg, x, row_off, w1_l, b1, w1_r,
                                                     nullptr, nullptr, hA, nullptr, N);
    // layer 2 (64 -> 64)
    agg_kernel<64><<<nb_n, 256, 0, stream>>>(hA, row_off, src_sorted, agg, N);
    xform_kernel<64, false><<<nb_n, 256, 0, stream>>>(agg, hA, row_off, w2_l, b2, w2_r,
                                                      nullptr, nullptr, hB, nullptr, N);
    // layer 3 (64 -> 64) + fused final FC (64 -> 3)
    agg_kernel<64><<<nb_n, 256, 0, stream>>>(hB, row_off, src_sorted, agg, N);
    xform_kernel<64, true><<<nb_n, 256, 0, stream>>>(agg, hB, row_off, w3_l, b3, w3_r,
                                                     fc_w, fc_b, nullptr, out, N);
}

// Round 2
// 746.619 us; speedup vs baseline: 2.2791x; 2.2791x over previous
//
#include <hip/hip_runtime.h>
#include <hip/hip_bf16.h>

#define N_NODES 100000
#define N_EDGES 1600000

__device__ __forceinline__ float bcast_lane(float v, int k) {
    return __int_as_float(__builtin_amdgcn_readlane(__float_as_int(v), k));
}

// ---------------- CSR build ----------------

__global__ void hist_kernel(const int* __restrict__ dst, int* __restrict__ deg, int e) {
    int i = blockIdx.x * blockDim.x + threadIdx.x;
    if (i < e) atomicAdd(&deg[dst[i]], 1);
}

// single-block scan, wave-shuffle based (1024 threads = 16 waves)
__global__ void scan_kernel(const int* __restrict__ deg, int* __restrict__ row_off,
                            int* __restrict__ cursor, int n) {
    __shared__ int wsum[16];
    __shared__ int carry_sh;
    int tid = threadIdx.x;
    int lane = tid & 63;
    int w = tid >> 6;
    if (tid == 0) carry_sh = 0;
    __syncthreads();
    for (int base = 0; base < n; base += 1024) {
        int i = base + tid;
        int d = (i < n) ? deg[i] : 0;
        // inclusive wave scan
        int v = d;
        #pragma unroll
        for (int off = 1; off < 64; off <<= 1) {
            int t = __shfl_up(v, off);
            if (lane >= off) v += t;
        }
        if (lane == 63) wsum[w] = v;
        __syncthreads();
        int woff = 0;
        for (int ww = 0; ww < w; ++ww) woff += wsum[ww];   // uniform LDS broadcast reads
        int carry = carry_sh;
        if (i < n) {
            int excl = carry + woff + v - d;
            row_off[i] = excl;
            cursor[i]  = excl;
        }
        __syncthreads();
        if (tid == 1023) carry_sh = carry + woff + v;      // chunk total added
        __syncthreads();
    }
    if (tid == 1023) row_off[n] = carry_sh;
}

__global__ void fill_kernel(const int* __restrict__ src, const int* __restrict__ dst,
                            int* __restrict__ cursor, int* __restrict__ src_sorted, int e) {
    int i = blockIdx.x * blockDim.x + threadIdx.x;
    if (i < e) {
        int pos = atomicAdd(&cursor[dst[i]], 1);
        src_sorted[pos] = src[i];
    }
}

// ---------------- neighbor sum (gather) ----------------
// one wave (64 lanes) per node; lane = channel

template <int C>
__global__ void agg_kernel(const float* __restrict__ xin, const int* __restrict__ row_off,
                           const int* __restrict__ src_sorted, float* __restrict__ agg, int n) {
    int wid  = (blockIdx.x * blockDim.x + threadIdx.x) >> 6;
    int lane = threadIdx.x & 63;
    if (wid >= n) return;
    int start = row_off[wid], end = row_off[wid + 1];
    float acc = 0.f;
    for (int base = start; base < end; base += 64) {
        int cnt = min(64, end - base);
        int sid = (lane < cnt) ? src_sorted[base + lane] : 0;
        for (int j = 0; j < cnt; ++j) {
            int s = __shfl(sid, j);
            if (lane < C) acc += xin[s * C + lane];
        }
    }
    if (lane < C) agg[wid * C + lane] = acc;
}

// ---------------- node transform ----------------
// h[lane] = relu( (agg[node]/deg) . w_l[lane][:] + b[lane] + hin[node] . w_r[lane][:] )
// weights held in VGPRs (one column pair per lane), input broadcast via v_readlane.
// grid-stride over nodes so the weight-register load is amortized.

template <int CIN, bool LAST>
__global__ void __launch_bounds__(256) xform_kernel(
        const float* __restrict__ agg, const float* __restrict__ hin,
        const int* __restrict__ row_off,
        const float* __restrict__ w_l, const float* __restrict__ b,
        const float* __restrict__ w_r,
        const float* __restrict__ fc_w, const float* __restrict__ fc_b,
        float* __restrict__ hout, float* __restrict__ out, int n) {
    int lane = threadIdx.x & 63;
    int gwid   = (blockIdx.x * blockDim.x + threadIdx.x) >> 6;
    int nwaves = (gridDim.x * blockDim.x) >> 6;

    // per-lane weight columns in registers
    float wl[CIN], wr[CIN];
    if (CIN % 4 == 0) {
        const float4* pl = reinterpret_cast<const float4*>(w_l + lane * CIN);
        const float4* pr = reinterpret_cast<const float4*>(w_r + lane * CIN);
        #pragma unroll
        for (int q = 0; q < CIN / 4; ++q) {
            float4 a = pl[q], c = pr[q];
            wl[4*q] = a.x; wl[4*q+1] = a.y; wl[4*q+2] = a.z; wl[4*q+3] = a.w;
            wr[4*q] = c.x; wr[4*q+1] = c.y; wr[4*q+2] = c.z; wr[4*q+3] = c.w;
        }
    } else {
        #pragma unroll
        for (int k = 0; k < CIN; ++k) { wl[k] = w_l[lane*CIN + k]; wr[k] = w_r[lane*CIN + k]; }
    }
    float bias = b[lane];
    float fw0 = 0.f, fw1 = 0.f, fw2 = 0.f;
    if (LAST) { fw0 = fc_w[lane]; fw1 = fc_w[64 + lane]; fw2 = fc_w[128 + lane]; }

    for (int node = gwid; node < n; node += nwaves) {
        int deg = row_off[node + 1] - row_off[node];
        float rs = 1.0f / (float)max(deg, 1);
        float av = (lane < CIN) ? agg[node * CIN + lane] * rs : 0.f;
        float hv = (lane < CIN) ? hin[node * CIN + lane] : 0.f;

        float acc = bias;
        #pragma unroll
        for (int k = 0; k < CIN; ++k) {
            float a = bcast_lane(av, k);
            float h = bcast_lane(hv, k);
            acc = fmaf(a, wl[k], fmaf(h, wr[k], acc));
        }
        float hval = fmaxf(acc, 0.f);

        if (!LAST) {
            hout[node * 64 + lane] = hval;
        } else {
            float p0 = hval * fw0, p1 = hval * fw1, p2 = hval * fw2;
            #pragma unroll
            for (int s = 32; s > 0; s >>= 1) {
                p0 += __shfl_xor(p0, s);
                p1 += __shfl_xor(p1, s);
                p2 += __shfl_xor(p2, s);
            }
            if (lane == 0) {
                out[node * 3 + 0] = p0 + fc_b[0];
                out[node * 3 + 1] = p1 + fc_b[1];
                out[node * 3 + 2] = p2 + fc_b[2];
            }
        }
    }
}

// ---------------- launch ----------------

extern "C" void kernel_launch(void* const* d_in, const int* in_sizes, int n_in,
                              void* d_out, int out_size, void* d_ws, size_t ws_size,
                              hipStream_t stream) {
    const float* x    = (const float*)d_in[0];
    const int*   ei   = (const int*)d_in[1];
    const float* w1_l = (const float*)d_in[2];
    const float* b1   = (const float*)d_in[3];
    const float* w1_r = (const float*)d_in[4];
    const float* w2_l = (const float*)d_in[5];
    const float* b2   = (const float*)d_in[6];
    const float* w2_r = (const float*)d_in[7];
    const float* w3_l = (const float*)d_in[8];
    const float* b3   = (const float*)d_in[9];
    const float* w3_r = (const float*)d_in[10];
    const float* fc_w = (const float*)d_in[11];
    const float* fc_b = (const float*)d_in[12];
    float* out = (float*)d_out;

    const int N = N_NODES;
    const int E = N_EDGES;
    const int* src = ei;
    const int* dst = ei + E;

    size_t off = 0;
    auto alloc = [&](size_t bytes) -> void* {
        void* p = (char*)d_ws + off;
        off += (bytes + 255) & ~size_t(255);
        return p;
    };
    int*   deg        = (int*)alloc(N * sizeof(int));
    int*   row_off    = (int*)alloc((N + 1) * sizeof(int));
    int*   cursor     = (int*)alloc(N * sizeof(int));
    int*   src_sorted = (int*)alloc(E * sizeof(int));
    float* agg        = (float*)alloc((size_t)N * 64 * sizeof(float));
    float* hA         = (float*)alloc((size_t)N * 64 * sizeof(float));
    float* hB         = (float*)alloc((size_t)N * 64 * sizeof(float));

    int nb_e = (E + 255) / 256;
    int nb_n = (N + 3) / 4;     // agg: 4 waves (nodes) per 256-thread block
    int nb_x = 1024;            // xform: grid-stride, 4096 waves

    hipMemsetAsync(deg, 0, N * sizeof(int), stream);
    hist_kernel<<<nb_e, 256, 0, stream>>>(dst, deg, E);
    scan_kernel<<<1, 1024, 0, stream>>>(deg, row_off, cursor, N);
    fill_kernel<<<nb_e, 256, 0, stream>>>(src, dst, cursor, src_sorted, E);

    // layer 1 (6 -> 64)
    agg_kernel<6><<<nb_n, 256, 0, stream>>>(x, row_off, src_sorted, agg, N);
    xform_kernel<6, false><<<nb_x, 256, 0, stream>>>(agg, x, row_off, w1_l, b1, w1_r,
                                                     nullptr, nullptr, hA, nullptr, N);
    // layer 2 (64 -> 64)
    agg_kernel<64><<<nb_n, 256, 0, stream>>>(hA, row_off, src_sorted, agg, N);
    xform_kernel<64, false><<<nb_x, 256, 0, stream>>>(agg, hA, row_off, w2_l, b2, w2_r,
                                                      nullptr, nullptr, hB, nullptr, N);
    // layer 3 (64 -> 64) + fused final FC (64 -> 3)
    agg_kernel<64><<<nb_n, 256, 0, stream>>>(hB, row_off, src_sorted, agg, N);
    xform_kernel<64, true><<<nb_x, 256, 0, stream>>>(agg, hB, row_off, w3_l, b3, w3_r,
                                                     fc_w, fc_b, nullptr, out, N);
}